// Round 9
// baseline (284.492 us; speedup 1.0000x reference)
//
#include <hip/hip_runtime.h>
#include <hip/hip_bf16.h>

#define NV 256                 // V
#define NC 64                  // C_OUT
#define VW 65536               // V*V
#define NE1 1048576            // N*C*V = 2^20
#define VB 32                  // v-chunk per block -> grid 8x64 = 512 = 2/CU

typedef __attribute__((ext_vector_type(8))) short bf16x8;   // 8 bf16 = 4 VGPRs
typedef __attribute__((ext_vector_type(16))) float f32x16;  // MFMA 32x32 acc
typedef __attribute__((ext_vector_type(4))) float f32x4;
typedef __attribute__((ext_vector_type(2))) unsigned int uint2v;

union U4 { unsigned int u[4]; bf16x8 v8; };

static __device__ __forceinline__ short f2bf(float x) {     // weights only
    union { __hip_bfloat16 b; short s; } u;
    u.b = __float2bfloat16(x);
    return u.s;
}
// one-inst RNE pack of two f32 -> 2xbf16
static __device__ __forceinline__ unsigned int cvt_pk_bf16(float a, float b) {
    unsigned int r;
    asm("v_cvt_pk_bf16_f32 %0, %1, %2" : "=v"(r) : "v"(a), "v"(b));
    return r;
}

// ---------------------------------------------------------------------------
// k1: xo_c[n][c][v] = bo[c] + sum_i wo[c][i] * xo[n][i][v]
// ---------------------------------------------------------------------------
__global__ __launch_bounds__(256) void k1_xoc(
    const float* __restrict__ xo, const float* __restrict__ wo,
    const float* __restrict__ bo, float* __restrict__ xoc)
{
    const int idx = blockIdx.x * 256 + threadIdx.x;   // < 2^20
    const int v = idx & 255;
    const int c = (idx >> 8) & 63;
    const int n = idx >> 14;
    const float* xon = xo + (size_t)n * 64 * NV;
    const float* wrow = wo + c * 64;                  // block-uniform -> s_load
    float s = bo[c];
#pragma unroll
    for (int i = 0; i < 64; ++i)
        s = fmaf(wrow[i], xon[i * NV + v], s);
    xoc[idx] = s;
}

// ---------------------------------------------------------------------------
// k2: math pipeline frozen (L1 scalar SGPR-weights; L2+L3 on 32x32x16 bf16
// MFMA with permlane32_swap fragment assembly; L3 bias as MFMA C-seed).
// NEW: v processed in PAIRS. Per pair, per ct-half (32 c): both v's MFMA
// epilogues fill a [32][2*256] LDS tile; the sweep then writes each c as
// 512 CONSECUTIVE floats (2KB contiguous run = 2 back-to-back dwordx4
// insts), doubling the HBM stream run-length vs R8. Gate partials via
// atomics (R6/R7 showed parity; saves 64MB of gpart traffic).
// Block = 4 waves x VB=32 v; grid = (8, 64) = 512 blocks = 2 resident/CU.
// ---------------------------------------------------------------------------
__global__ __launch_bounds__(256) void k2_mfma(
    const float* __restrict__ A,
    const float* __restrict__ w1, const float* __restrict__ b1,
    const float* __restrict__ w2, const float* __restrict__ b2,
    const float* __restrict__ w3, const float* __restrict__ b3,
    const float* __restrict__ xoc,
    float* __restrict__ Aout, float* __restrict__ post)
{
    __shared__ float stage[32 * 512];            // 64 KB: [c_local][s*256+w]
    __shared__ float xocs[NC][VB];               // 8 KB

    const int t    = threadIdx.x;
    const int wt   = t >> 6;
    const int lane = t & 63;
    const int lo   = lane & 31;
    const int hi   = lane >> 5;
    const int vbase = blockIdx.x * VB;
    const int n    = blockIdx.y;
    const int w0   = wt << 6;

    for (int e = t; e < NC * VB; e += 256) {
        const int c = e >> 5, j = e & (VB - 1);
        xocs[c][j] = xoc[(size_t)n * (NC * NV) + c * NV + vbase + j];
    }
    __syncthreads();

    // W3 A-fragments: lane(lo,hi) holds w3[c=32ct+lo][k=16h+8hi+e]
    bf16x8 af[2][2];
#pragma unroll
    for (int ct = 0; ct < 2; ++ct)
#pragma unroll
        for (int h = 0; h < 2; ++h) {
            const float* wp = w3 + ((ct << 5) + lo) * 32 + (h << 4) + (hi << 3);
            bf16x8 pk;
#pragma unroll
            for (int e = 0; e < 8; ++e) pk[e] = f2bf(wp[e]);
            af[ct][h] = pk;
        }
    // W2 A-fragment: lane(lo,hi) holds w2[row=lo][k=8hi+e]  (K=16)
    bf16x8 af2;
#pragma unroll
    for (int e = 0; e < 8; ++e) af2[e] = f2bf(w2[lo * 16 + (hi << 3) + e]);

    // layer-3 bias as accumulator seed
    f32x16 dinit[2];
#pragma unroll
    for (int ct = 0; ct < 2; ++ct)
#pragma unroll
        for (int r = 0; r < 16; ++r)
            dinit[ct][r] = b3[(ct << 5) + (r & 3) + ((r >> 2) << 3) + (hi << 2)];

    float gacc[2][2][16];
#pragma unroll
    for (int ct = 0; ct < 2; ++ct)
#pragma unroll
        for (int T = 0; T < 2; ++T)
#pragma unroll
            for (int r = 0; r < 16; ++r) gacc[ct][T][r] = 0.0f;

    const float* An  = A    + (size_t)n * 6 * VW;
    float*       Aon = Aout + (size_t)n * NC * VW;
    const float NLOG2E = -1.4426950408889634f;

    // rolling prefetch of both rows' 5 A-planes for pair 0
    const float* ap0 = An + (size_t)vbase * NV + w0 + lane;
    float a0[5], a1[5];
#pragma unroll
    for (int pl = 0; pl < 5; ++pl) {
        a0[pl] = ap0[(size_t)pl * VW];
        a1[pl] = ap0[(size_t)pl * VW + NV];
    }

    for (int vp = 0; vp < VB / 2; ++vp) {
        const int v0 = vbase + (vp << 1);

        // prefetch next pair (redundant on last iter; uniform)
        const float* apn = ap0 + (size_t)((vp + 1 < VB / 2 ? vp + 1 : vp) << 1) * NV;
        float na0[5], na1[5];
#pragma unroll
        for (int pl = 0; pl < 5; ++pl) {
            na0[pl] = apn[(size_t)pl * VW];
            na1[pl] = apn[(size_t)pl * VW + NV];
        }

        // ===== layers 1-2 + fragment assembly for both pair members =======
        U4 b3fv[2][2][2];                       // [s][T][h]
#pragma unroll
        for (int s = 0; s < 2; ++s) {
            const float* aa = (s == 0) ? a0 : a1;
            unsigned int h1p[8];
#pragma unroll
            for (int m = 0; m < 8; ++m) {
                float sa = b1[2 * m];
                float sb = b1[2 * m + 1];
#pragma unroll
                for (int i = 0; i < 5; ++i) {
                    sa = fmaf(w1[(2 * m) * 5 + i],     aa[i], sa);
                    sb = fmaf(w1[(2 * m + 1) * 5 + i], aa[i], sb);
                }
                h1p[m] = cvt_pk_bf16(fmaxf(sa, 0.0f), fmaxf(sb, 0.0f));
            }
            U4 b1T0, b1T1;
#pragma unroll
            for (int j = 0; j < 4; ++j) {
                uint2v r = __builtin_amdgcn_permlane32_swap(h1p[j], h1p[4 + j],
                                                            false, false);
                b1T0.u[j] = r.x;
                b1T1.u[j] = r.y;
            }
            f32x16 d20, d21;
#pragma unroll
            for (int r = 0; r < 16; ++r) {
                const float bv = b2[(r & 3) + ((r >> 2) << 3) + (hi << 2)];
                d20[r] = bv; d21[r] = bv;
            }
            d20 = __builtin_amdgcn_mfma_f32_32x32x16_bf16(af2, b1T0.v8, d20, 0, 0, 0);
            d21 = __builtin_amdgcn_mfma_f32_32x32x16_bf16(af2, b1T1.v8, d21, 0, 0, 0);

            unsigned int p[8], q[8];
#pragma unroll
            for (int j = 0; j < 8; ++j) {
                p[j] = cvt_pk_bf16(fmaxf(d20[2 * j], 0.0f), fmaxf(d20[2 * j + 1], 0.0f));
                q[j] = cvt_pk_bf16(fmaxf(d21[2 * j], 0.0f), fmaxf(d21[2 * j + 1], 0.0f));
            }
#pragma unroll
            for (int h = 0; h < 2; ++h) {
                uint2v r02 = __builtin_amdgcn_permlane32_swap(p[4 * h + 0], p[4 * h + 2], false, false);
                uint2v r13 = __builtin_amdgcn_permlane32_swap(p[4 * h + 1], p[4 * h + 3], false, false);
                b3fv[s][0][h].u[0] = r02.x; b3fv[s][0][h].u[2] = r02.y;
                b3fv[s][0][h].u[1] = r13.x; b3fv[s][0][h].u[3] = r13.y;
                uint2v s02 = __builtin_amdgcn_permlane32_swap(q[4 * h + 0], q[4 * h + 2], false, false);
                uint2v s13 = __builtin_amdgcn_permlane32_swap(q[4 * h + 1], q[4 * h + 3], false, false);
                b3fv[s][1][h].u[0] = s02.x; b3fv[s][1][h].u[2] = s02.y;
                b3fv[s][1][h].u[1] = s13.x; b3fv[s][1][h].u[3] = s13.y;
            }
        }

        // ===== per ct-half: both v's MFMA+epilogue -> stage; 2KB sweeps ====
#pragma unroll
        for (int ct = 0; ct < 2; ++ct) {
#pragma unroll
            for (int s = 0; s < 2; ++s) {
                f32x16 d0 = dinit[ct], d1 = dinit[ct];
                d0 = __builtin_amdgcn_mfma_f32_32x32x16_bf16(af[ct][0], b3fv[s][0][0].v8, d0, 0, 0, 0);
                d0 = __builtin_amdgcn_mfma_f32_32x32x16_bf16(af[ct][1], b3fv[s][0][1].v8, d0, 0, 0, 0);
                d1 = __builtin_amdgcn_mfma_f32_32x32x16_bf16(af[ct][0], b3fv[s][1][0].v8, d1, 0, 0, 0);
                d1 = __builtin_amdgcn_mfma_f32_32x32x16_bf16(af[ct][1], b3fv[s][1][1].v8, d1, 0, 0, 0);
#pragma unroll
                for (int r = 0; r < 16; ++r) {
                    const int cl = (r & 3) + ((r >> 2) << 3) + (hi << 2);  // 0..31
                    const int c  = (ct << 5) + cl;
                    const float vx = __builtin_amdgcn_rcpf(
                        1.0f + __builtin_amdgcn_exp2f(d0[r] * NLOG2E));
                    const float vy = __builtin_amdgcn_rcpf(
                        1.0f + __builtin_amdgcn_exp2f(d1[r] * NLOG2E));
                    stage[cl * 512 + (s << 8) + w0 + lo]      = vx;  // T0
                    stage[cl * 512 + (s << 8) + w0 + 32 + lo] = vy;  // T1
                    const int vi = (vp << 1) + s;
                    gacc[ct][0][r] = fmaf(xocs[c][vi], vx, gacc[ct][0][r]);
                    gacc[ct][1][r] = fmaf(xocs[c][vi], vy, gacc[ct][1][r]);
                }
            }
            __syncthreads();
            // sweep: 8 c's per wave, each 512 consecutive floats (2KB run)
#pragma unroll
            for (int k = 0; k < 8; ++k) {
                const int cl = (k << 2) + wt;
                const f32x4 u0 = *(const f32x4*)&stage[cl * 512 + (lane << 2)];
                const f32x4 u1 = *(const f32x4*)&stage[cl * 512 + 256 + (lane << 2)];
                float* dst = Aon + (size_t)((ct << 5) + cl) * VW
                                 + (size_t)v0 * NV + (lane << 2);
                __builtin_nontemporal_store(u0, (f32x4*)dst);
                __builtin_nontemporal_store(u1, (f32x4*)(dst + 256));
            }
            __syncthreads();   // protect stage for next ct / next pair
        }

#pragma unroll
        for (int pl = 0; pl < 5; ++pl) { a0[pl] = na0[pl]; a1[pl] = na1[pl]; }
    }

    // ---- gate: one atomic pass per block (8 blocks collide per address)
    float* pn = post + (size_t)n * (NC * NV) + w0;
#pragma unroll
    for (int ct = 0; ct < 2; ++ct)
#pragma unroll
        for (int T = 0; T < 2; ++T)
#pragma unroll
            for (int r = 0; r < 16; ++r) {
                const int c = (ct << 5) + (r & 3) + ((r >> 2) << 3) + (hi << 2);
                atomicAdd(pn + c * NV + (T << 5) + lo, gacc[ct][T][r]);
            }
}

// ---------------------------------------------------------------------------
// k3: out1 = x * sigmoid(post)
// ---------------------------------------------------------------------------
__global__ __launch_bounds__(256) void k3_gate(
    const float* __restrict__ x, const float* __restrict__ post,
    float* __restrict__ out1)
{
    const int idx = blockIdx.x * 256 + threadIdx.x;   // < 2^20
    const float p = 1.0f / (1.0f + __expf(-post[idx]));
    out1[idx] = x[idx] * p;
}

extern "C" void kernel_launch(void* const* d_in, const int* in_sizes, int n_in,
                              void* d_out, int out_size, void* d_ws, size_t ws_size,
                              hipStream_t stream)
{
    const float* x  = (const float*)d_in[0];
    const float* xo = (const float*)d_in[1];
    const float* A  = (const float*)d_in[2];
    const float* w1 = (const float*)d_in[3];
    const float* b1 = (const float*)d_in[4];
    const float* w2 = (const float*)d_in[5];
    const float* b2 = (const float*)d_in[6];
    const float* w3 = (const float*)d_in[7];
    const float* b3 = (const float*)d_in[8];
    const float* wo = (const float*)d_in[9];
    const float* bo = (const float*)d_in[10];

    float* out1 = (float*)d_out;
    float* Aout = (float*)d_out + NE1;

    float* xoc  = (float*)d_ws;                 // 4 MB
    float* post = (float*)d_ws + NE1;           // 4 MB gate accumulator

    hipMemsetAsync(post, 0, (size_t)NE1 * sizeof(float), stream);
    k1_xoc<<<NE1 / 256, 256, 0, stream>>>(xo, wo, bo, xoc);
    k2_mfma<<<dim3(NV / VB, 64), 256, 0, stream>>>(A, w1, b1, w2, b2, w3, b3,
                                                   xoc, Aout, post);
    k3_gate<<<NE1 / 256, 256, 0, stream>>>(x, post, out1);
}

// Round 10
// 266.356 us; speedup vs baseline: 1.0681x; 1.0681x over previous
//
#include <hip/hip_runtime.h>
#include <hip/hip_bf16.h>

#define NV 256                 // V
#define NC 64                  // C_OUT
#define VW 65536               // V*V
#define NE1 1048576            // N*C*V = 2^20
#define VB 32                  // v-chunk per block -> grid 8x64 = 512 = 2/CU

typedef __attribute__((ext_vector_type(8))) short bf16x8;   // 8 bf16 = 4 VGPRs
typedef __attribute__((ext_vector_type(16))) float f32x16;  // MFMA 32x32 acc
typedef __attribute__((ext_vector_type(4))) float f32x4;
typedef __attribute__((ext_vector_type(2))) unsigned int uint2v;

union U4 { unsigned int u[4]; bf16x8 v8; };

static __device__ __forceinline__ short f2bf(float x) {     // weights only
    union { __hip_bfloat16 b; short s; } u;
    u.b = __float2bfloat16(x);
    return u.s;
}
// one-inst RNE pack of two f32 -> 2xbf16
static __device__ __forceinline__ unsigned int cvt_pk_bf16(float a, float b) {
    unsigned int r;
    asm("v_cvt_pk_bf16_f32 %0, %1, %2" : "=v"(r) : "v"(a), "v"(b));
    return r;
}

// ---------------------------------------------------------------------------
// k1: xo_c[n][c][v] = bo[c] + sum_i wo[c][i] * xo[n][i][v]
// ---------------------------------------------------------------------------
__global__ __launch_bounds__(256) void k1_xoc(
    const float* __restrict__ xo, const float* __restrict__ wo,
    const float* __restrict__ bo, float* __restrict__ xoc)
{
    const int idx = blockIdx.x * 256 + threadIdx.x;   // < 2^20
    const int v = idx & 255;
    const int c = (idx >> 8) & 63;
    const int n = idx >> 14;
    const float* xon = xo + (size_t)n * 64 * NV;
    const float* wrow = wo + c * 64;                  // block-uniform -> s_load
    float s = bo[c];
#pragma unroll
    for (int i = 0; i < 64; ++i)
        s = fmaf(wrow[i], xon[i * NV + v], s);
    xoc[idx] = s;
}

// ---------------------------------------------------------------------------
// k2: R8 structure verbatim (best measured: 263 µs). Math pipeline: L1
// scalar SGPR-weights; L2+L3 on 32x32x16 bf16 MFMA with permlane32_swap
// fragment assembly; L3 bias as MFMA C-seed. Output path: per-vi epilogue
// -> 64KB LDS stage[c][w]; sweep stores full (c,v) rows as 1KB nontemporal
// dwordx4. Gate: single atomicAdd pass per block (R9's isolated good
// change; drops the 32MB gpart write + 32MB k3 re-read of the partial
// path). Block = 4 waves x VB=32 v; grid = (8, 64) = 512 = 2/CU.
// ---------------------------------------------------------------------------
__global__ __launch_bounds__(256) void k2_mfma(
    const float* __restrict__ A,
    const float* __restrict__ w1, const float* __restrict__ b1,
    const float* __restrict__ w2, const float* __restrict__ b2,
    const float* __restrict__ w3, const float* __restrict__ b3,
    const float* __restrict__ xoc,
    float* __restrict__ Aout, float* __restrict__ post)
{
    __shared__ float stage[NC * NV];             // 64 KB: [c][w] for one v
    __shared__ float xocs[NC][VB];               // 8 KB

    const int t    = threadIdx.x;
    const int wt   = t >> 6;
    const int lane = t & 63;
    const int lo   = lane & 31;
    const int hi   = lane >> 5;
    const int vbase = blockIdx.x * VB;
    const int n    = blockIdx.y;
    const int w0   = wt << 6;

    for (int e = t; e < NC * VB; e += 256) {
        const int c = e >> 5, j = e & (VB - 1);
        xocs[c][j] = xoc[(size_t)n * (NC * NV) + c * NV + vbase + j];
    }
    __syncthreads();

    // W3 A-fragments: lane(lo,hi) holds w3[c=32ct+lo][k=16h+8hi+e]
    bf16x8 af[2][2];
#pragma unroll
    for (int ct = 0; ct < 2; ++ct)
#pragma unroll
        for (int h = 0; h < 2; ++h) {
            const float* wp = w3 + ((ct << 5) + lo) * 32 + (h << 4) + (hi << 3);
            bf16x8 pk;
#pragma unroll
            for (int e = 0; e < 8; ++e) pk[e] = f2bf(wp[e]);
            af[ct][h] = pk;
        }
    // W2 A-fragment: lane(lo,hi) holds w2[row=lo][k=8hi+e]  (K=16)
    bf16x8 af2;
#pragma unroll
    for (int e = 0; e < 8; ++e) af2[e] = f2bf(w2[lo * 16 + (hi << 3) + e]);

    // layer-3 bias as accumulator seed: dinit[ct][r] = b3[c(ct,r,hi)]
    f32x16 dinit[2];
#pragma unroll
    for (int ct = 0; ct < 2; ++ct)
#pragma unroll
        for (int r = 0; r < 16; ++r)
            dinit[ct][r] = b3[(ct << 5) + (r & 3) + ((r >> 2) << 3) + (hi << 2)];

    float gacc[2][2][16];
#pragma unroll
    for (int ct = 0; ct < 2; ++ct)
#pragma unroll
        for (int T = 0; T < 2; ++T)
#pragma unroll
            for (int r = 0; r < 16; ++r) gacc[ct][T][r] = 0.0f;

    const float* An  = A    + (size_t)n * 6 * VW;
    float*       Aon = Aout + (size_t)n * NC * VW;
    const float NLOG2E = -1.4426950408889634f;

    // software prefetch of the 5 A-planes for vi=0
    const float* ap0 = An + (size_t)vbase * NV + w0 + lane;
    float a0 = ap0[0], a1 = ap0[VW], a2 = ap0[2 * VW],
          a3 = ap0[3 * VW], a4 = ap0[4 * VW];

    for (int vi = 0; vi < VB; ++vi) {
        const int v = vbase + vi;

        const int vn = (vi + 1 < VB) ? (vi + 1) : vi;
        const float* apn = ap0 + (size_t)vn * NV;
        const float na0 = apn[0], na1 = apn[VW], na2 = apn[2 * VW],
                    na3 = apn[3 * VW], na4 = apn[4 * VW];

        // ===== layer 1 (5->16), scalar; weights are SGPR =====
        unsigned int h1p[8];
#pragma unroll
        for (int m = 0; m < 8; ++m) {
            float sa = b1[2 * m];
            float sb = b1[2 * m + 1];
            sa = fmaf(w1[(2 * m) * 5 + 0], a0, sa);
            sa = fmaf(w1[(2 * m) * 5 + 1], a1, sa);
            sa = fmaf(w1[(2 * m) * 5 + 2], a2, sa);
            sa = fmaf(w1[(2 * m) * 5 + 3], a3, sa);
            sa = fmaf(w1[(2 * m) * 5 + 4], a4, sa);
            sb = fmaf(w1[(2 * m + 1) * 5 + 0], a0, sb);
            sb = fmaf(w1[(2 * m + 1) * 5 + 1], a1, sb);
            sb = fmaf(w1[(2 * m + 1) * 5 + 2], a2, sb);
            sb = fmaf(w1[(2 * m + 1) * 5 + 3], a3, sb);
            sb = fmaf(w1[(2 * m + 1) * 5 + 4], a4, sb);
            h1p[m] = cvt_pk_bf16(fmaxf(sa, 0.0f), fmaxf(sb, 0.0f));
        }

        // ===== layer 2 (16->32) on MFMA =====
        U4 b1T0, b1T1;
#pragma unroll
        for (int j = 0; j < 4; ++j) {
            uint2v r = __builtin_amdgcn_permlane32_swap(h1p[j], h1p[4 + j],
                                                        false, false);
            b1T0.u[j] = r.x;
            b1T1.u[j] = r.y;
        }
        f32x16 d20, d21;
#pragma unroll
        for (int r = 0; r < 16; ++r) {
            const float bv = b2[(r & 3) + ((r >> 2) << 3) + (hi << 2)];
            d20[r] = bv; d21[r] = bv;
        }
        d20 = __builtin_amdgcn_mfma_f32_32x32x16_bf16(af2, b1T0.v8, d20, 0, 0, 0);
        d21 = __builtin_amdgcn_mfma_f32_32x32x16_bf16(af2, b1T1.v8, d21, 0, 0, 0);

        unsigned int p[8], q[8];
#pragma unroll
        for (int j = 0; j < 8; ++j) {
            p[j] = cvt_pk_bf16(fmaxf(d20[2 * j], 0.0f), fmaxf(d20[2 * j + 1], 0.0f));
            q[j] = cvt_pk_bf16(fmaxf(d21[2 * j], 0.0f), fmaxf(d21[2 * j + 1], 0.0f));
        }
        U4 b3f[2][2];
#pragma unroll
        for (int h = 0; h < 2; ++h) {
            uint2v r02 = __builtin_amdgcn_permlane32_swap(p[4 * h + 0], p[4 * h + 2], false, false);
            uint2v r13 = __builtin_amdgcn_permlane32_swap(p[4 * h + 1], p[4 * h + 3], false, false);
            b3f[0][h].u[0] = r02.x; b3f[0][h].u[2] = r02.y;
            b3f[0][h].u[1] = r13.x; b3f[0][h].u[3] = r13.y;
            uint2v s02 = __builtin_amdgcn_permlane32_swap(q[4 * h + 0], q[4 * h + 2], false, false);
            uint2v s13 = __builtin_amdgcn_permlane32_swap(q[4 * h + 1], q[4 * h + 3], false, false);
            b3f[1][h].u[0] = s02.x; b3f[1][h].u[2] = s02.y;
            b3f[1][h].u[1] = s13.x; b3f[1][h].u[3] = s13.y;
        }

        // ===== layer 3 MFMA; epilogue -> LDS stage tile ====================
#pragma unroll
        for (int ct = 0; ct < 2; ++ct) {
            f32x16 d0 = dinit[ct], d1 = dinit[ct];
            d0 = __builtin_amdgcn_mfma_f32_32x32x16_bf16(af[ct][0], b3f[0][0].v8, d0, 0, 0, 0);
            d0 = __builtin_amdgcn_mfma_f32_32x32x16_bf16(af[ct][1], b3f[0][1].v8, d0, 0, 0, 0);
            d1 = __builtin_amdgcn_mfma_f32_32x32x16_bf16(af[ct][0], b3f[1][0].v8, d1, 0, 0, 0);
            d1 = __builtin_amdgcn_mfma_f32_32x32x16_bf16(af[ct][1], b3f[1][1].v8, d1, 0, 0, 0);
#pragma unroll
            for (int r = 0; r < 16; ++r) {
                const int c = (ct << 5) + (r & 3) + ((r >> 2) << 3) + (hi << 2);
                const float vx = __builtin_amdgcn_rcpf(
                    1.0f + __builtin_amdgcn_exp2f(d0[r] * NLOG2E));
                const float vy = __builtin_amdgcn_rcpf(
                    1.0f + __builtin_amdgcn_exp2f(d1[r] * NLOG2E));
                stage[c * NV + w0 + lo]      = vx;   // T0 tile, 2-way alias
                stage[c * NV + w0 + 32 + lo] = vy;   // T1 tile
                gacc[ct][0][r] = fmaf(xocs[c][vi], vx, gacc[ct][0][r]);
                gacc[ct][1][r] = fmaf(xocs[c][vi], vy, gacc[ct][1][r]);
            }
        }
        __syncthreads();

        // ===== sweep: each wave stores full (c,v) rows as 1KB dwordx4 ======
#pragma unroll
        for (int k = 0; k < 16; ++k) {
            const int c = (k << 2) + wt;
            const f32x4 val = *(const f32x4*)&stage[c * NV + (lane << 2)];
            __builtin_nontemporal_store(
                val, (f32x4*)(Aon + (size_t)c * VW + (size_t)v * NV + (lane << 2)));
        }
        __syncthreads();   // protect stage before next vi's writes

        a0 = na0; a1 = na1; a2 = na2; a3 = na3; a4 = na4;
    }

    // ---- gate: one atomic pass per block (8 blocks collide per address)
    float* pn = post + (size_t)n * (NC * NV) + w0;
#pragma unroll
    for (int ct = 0; ct < 2; ++ct)
#pragma unroll
        for (int T = 0; T < 2; ++T)
#pragma unroll
            for (int r = 0; r < 16; ++r) {
                const int c = (ct << 5) + (r & 3) + ((r >> 2) << 3) + (hi << 2);
                atomicAdd(pn + c * NV + (T << 5) + lo, gacc[ct][T][r]);
            }
}

// ---------------------------------------------------------------------------
// k3: out1 = x * sigmoid(post)
// ---------------------------------------------------------------------------
__global__ __launch_bounds__(256) void k3_gate(
    const float* __restrict__ x, const float* __restrict__ post,
    float* __restrict__ out1)
{
    const int idx = blockIdx.x * 256 + threadIdx.x;   // < 2^20
    const float p = 1.0f / (1.0f + __expf(-post[idx]));
    out1[idx] = x[idx] * p;
}

extern "C" void kernel_launch(void* const* d_in, const int* in_sizes, int n_in,
                              void* d_out, int out_size, void* d_ws, size_t ws_size,
                              hipStream_t stream)
{
    const float* x  = (const float*)d_in[0];
    const float* xo = (const float*)d_in[1];
    const float* A  = (const float*)d_in[2];
    const float* w1 = (const float*)d_in[3];
    const float* b1 = (const float*)d_in[4];
    const float* w2 = (const float*)d_in[5];
    const float* b2 = (const float*)d_in[6];
    const float* w3 = (const float*)d_in[7];
    const float* b3 = (const float*)d_in[8];
    const float* wo = (const float*)d_in[9];
    const float* bo = (const float*)d_in[10];

    float* out1 = (float*)d_out;
    float* Aout = (float*)d_out + NE1;

    float* xoc  = (float*)d_ws;                 // 4 MB
    float* post = (float*)d_ws + NE1;           // 4 MB gate accumulator

    hipMemsetAsync(post, 0, (size_t)NE1 * sizeof(float), stream);
    k1_xoc<<<NE1 / 256, 256, 0, stream>>>(xo, wo, bo, xoc);
    k2_mfma<<<dim3(NV / VB, 64), 256, 0, stream>>>(A, w1, b1, w2, b2, w3, b3,
                                                   xoc, Aout, post);
    k3_gate<<<NE1 / 256, 256, 0, stream>>>(x, post, out1);
}